// Round 1
// baseline (881.867 us; speedup 1.0000x reference)
//
#include <hip/hip_runtime.h>
#include <math.h>

#define N_ROWS (16 * 16384)          // 262144 rows
#define D 64
#define K 512
#define BLOCK 256
#define RPT 2                        // rows per thread
#define ROWS_PER_BLOCK (BLOCK * RPT) // 512
#define GRID (N_ROWS / ROWS_PER_BLOCK)  // 512 blocks -> 2 per CU

// d_out layout (float element offsets), outputs concatenated in return order:
// vq_loss[1], quantized_st[N*D], perplexity[1], encodings[N*K], indices[N]
#define OFF_LOSS 0ULL
#define OFF_Q    1ULL
#define OFF_PERP (1ULL + (unsigned long long)N_ROWS * D)        // 16777217
#define OFF_ENC  (OFF_PERP + 1ULL)                               // 16777218
#define OFF_IDX  (OFF_ENC + (unsigned long long)N_ROWS * K)      // 150994946

typedef float f32x16 __attribute__((ext_vector_type(16)));

// 8 FMAs for one float4 of e against both rows; accumulation order per chain
// is identical to the previous passing kernel (a0.x..a0.w, a1.x..a1.w).
#define FMA_I(EV, II, XI) do {                                   \
    const float ex_ = (EV)[4*(II)+0];                            \
    const float ey_ = (EV)[4*(II)+1];                            \
    const float ez_ = (EV)[4*(II)+2];                            \
    const float ew_ = (EV)[4*(II)+3];                            \
    a0.x = fmaf(xa[XI].x, ex_, a0.x);                            \
    a0.y = fmaf(xa[XI].y, ey_, a0.y);                            \
    a0.z = fmaf(xa[XI].z, ez_, a0.z);                            \
    a0.w = fmaf(xa[XI].w, ew_, a0.w);                            \
    a1.x = fmaf(xb[XI].x, ex_, a1.x);                            \
    a1.y = fmaf(xb[XI].y, ey_, a1.y);                            \
    a1.z = fmaf(xb[XI].z, ez_, a1.z);                            \
    a1.w = fmaf(xb[XI].w, ew_, a1.w);                            \
} while (0)

__global__ __launch_bounds__(BLOCK)
__attribute__((amdgpu_waves_per_eu(2, 2)))
void vq_main(
    const float* __restrict__ x, const float* __restrict__ emb,
    float* __restrict__ out, float* __restrict__ ws_loss,
    unsigned int* __restrict__ ws_hist)
{
    __shared__ float lds_se[K];               // 2 KB ||e||^2
    __shared__ unsigned int lds_hist[K];      // 2 KB histogram
    __shared__ float lds_red[BLOCK / 64];

    const int tid = threadIdx.x;
    const int bid = blockIdx.x;
    const int row0 = bid * ROWS_PER_BLOCK + tid;          // thread's row A
    const int row1 = row0 + BLOCK;                        // thread's row B

    lds_hist[tid] = 0;
    lds_hist[tid + BLOCK] = 0;

    // ---- ||e||^2 table once per block (same FMA order as before - passed) ----
    for (int k = tid; k < K; k += BLOCK) {
        const float4* e4 = (const float4*)(emb + (size_t)k * D);
        float s = 0.f;
        #pragma unroll
        for (int i = 0; i < 16; i++) {
            float4 e = e4[i];
            s = fmaf(e.x, e.x, s); s = fmaf(e.y, e.y, s);
            s = fmaf(e.z, e.z, s); s = fmaf(e.w, e.w, s);
        }
        lds_se[k] = s;
    }

    // ---- two rows into registers (32 x float4 = 128 VGPR) ----
    float4 xa[16], xb[16];
    {
        const float4* pa = (const float4*)(x + (size_t)row0 * D);
        const float4* pb = (const float4*)(x + (size_t)row1 * D);
        #pragma unroll
        for (int i = 0; i < 16; i++) { xa[i] = pa[i]; xb[i] = pb[i]; }
    }

    // sx per row, same accumulation order as before
    float sxa, sxb;
    {
        float4 sa = make_float4(0.f, 0.f, 0.f, 0.f);
        float4 sb = make_float4(0.f, 0.f, 0.f, 0.f);
        #pragma unroll
        for (int i = 0; i < 16; i++) {
            sa.x = fmaf(xa[i].x, xa[i].x, sa.x);
            sa.y = fmaf(xa[i].y, xa[i].y, sa.y);
            sa.z = fmaf(xa[i].z, xa[i].z, sa.z);
            sa.w = fmaf(xa[i].w, xa[i].w, sa.w);
            sb.x = fmaf(xb[i].x, xb[i].x, sb.x);
            sb.y = fmaf(xb[i].y, xb[i].y, sb.y);
            sb.z = fmaf(xb[i].z, xb[i].z, sb.z);
            sb.w = fmaf(xb[i].w, xb[i].w, sb.w);
        }
        sxa = (sa.x + sa.y) + (sa.z + sa.w);
        sxb = (sb.x + sb.y) + (sb.z + sb.w);
    }

    __syncthreads();   // lds_se / lds_hist ready

    // one-hot block region (even float offset -> 8B aligned)
    float2* encb = (float2*)(out + OFF_ENC + (size_t)bid * ROWS_PER_BLOCK * K);
    const float2 z2 = make_float2(0.f, 0.f);

    float bestA = __builtin_inff(), bestB = __builtin_inff();
    int bkA = 0, bkB = 0;

    // ---- argmin over codebook: codebook rows via SCALAR loads (SGPRs) ----
    // Address is wave-uniform; 4x s_load_dwordx16 replaces 16x ds_read_b128.
    // SMEM returns out-of-order -> lgkmcnt(0) INSIDE the asm block so the
    // "=s" outputs are complete before any consumer can be scheduled.
    #pragma unroll 1
    for (int k = 0; k < K; k++) {
        // paced zero-fill: exactly one float2 store per code iteration
        // (k doubles as the row-within-block index for the zero region)
        encb[(size_t)k * BLOCK + tid] = z2;

        const float* ep = emb + (size_t)k * D;
        f32x16 e0, e1, e2, e3;
        asm volatile(
            "s_load_dwordx16 %0, %4, 0x0\n\t"
            "s_load_dwordx16 %1, %4, 0x40\n\t"
            "s_load_dwordx16 %2, %4, 0x80\n\t"
            "s_load_dwordx16 %3, %4, 0xC0\n\t"
            "s_waitcnt lgkmcnt(0)"
            : "=s"(e0), "=s"(e1), "=s"(e2), "=s"(e3)
            : "s"(ep));

        float4 a0 = make_float4(0.f, 0.f, 0.f, 0.f);
        float4 a1 = make_float4(0.f, 0.f, 0.f, 0.f);
        #pragma unroll
        for (int i = 0; i < 4; i++) FMA_I(e0, i, i);
        #pragma unroll
        for (int i = 0; i < 4; i++) FMA_I(e1, i, 4 + i);
        #pragma unroll
        for (int i = 0; i < 4; i++) FMA_I(e2, i, 8 + i);
        #pragma unroll
        for (int i = 0; i < 4; i++) FMA_I(e3, i, 12 + i);

        float dot0 = (a0.x + a0.y) + (a0.z + a0.w);
        float dot1 = (a1.x + a1.y) + (a1.z + a1.w);
        float se = lds_se[k];
        // reference rounding: t = (sx + se) rounds; d = t - 2*dot (one fma)
        float d0 = fmaf(-2.0f, dot0, sxa + se);
        float d1 = fmaf(-2.0f, dot1, sxb + se);
        if (d0 < bestA) { bestA = d0; bkA = k; }  // strict < = first-min
        if (d1 < bestB) { bestB = d1; bkB = k; }
    }

    // ---- index outputs (as float) ----
    out[OFF_IDX + (size_t)row0] = (float)bkA;
    out[OFF_IDX + (size_t)row1] = (float)bkB;

    // ---- quantized outputs + loss (region base 4B-aligned -> scalar stores) ----
    float loss = 0.f;
    {
        const float4* ea = (const float4*)(emb + (size_t)bkA * D);
        float* q = out + OFF_Q + (size_t)row0 * D;
        #pragma unroll
        for (int i = 0; i < 16; i++) {
            float4 e = ea[i];
            q[i * 4 + 0] = e.x; q[i * 4 + 1] = e.y;
            q[i * 4 + 2] = e.z; q[i * 4 + 3] = e.w;
            float d0 = e.x - xa[i].x, d1 = e.y - xa[i].y;
            float d2 = e.z - xa[i].z, d3 = e.w - xa[i].w;
            loss = fmaf(d0, d0, loss); loss = fmaf(d1, d1, loss);
            loss = fmaf(d2, d2, loss); loss = fmaf(d3, d3, loss);
        }
        const float4* eb = (const float4*)(emb + (size_t)bkB * D);
        q = out + OFF_Q + (size_t)row1 * D;
        #pragma unroll
        for (int i = 0; i < 16; i++) {
            float4 e = eb[i];
            q[i * 4 + 0] = e.x; q[i * 4 + 1] = e.y;
            q[i * 4 + 2] = e.z; q[i * 4 + 3] = e.w;
            float d0 = e.x - xb[i].x, d1 = e.y - xb[i].y;
            float d2 = e.z - xb[i].z, d3 = e.w - xb[i].w;
            loss = fmaf(d0, d0, loss); loss = fmaf(d1, d1, loss);
            loss = fmaf(d2, d2, loss); loss = fmaf(d3, d3, loss);
        }
    }

    // wave reduce then block reduce for loss; LDS histogram
    for (int off = 32; off; off >>= 1) loss += __shfl_down(loss, off, 64);
    const int wave = tid >> 6, lane = tid & 63;
    if (lane == 0) lds_red[wave] = loss;
    atomicAdd(&lds_hist[bkA], 1u);
    atomicAdd(&lds_hist[bkB], 1u);
    __syncthreads();  // drains all zero-fill stores (vmcnt(0) before s_barrier)
    if (tid == 0) {
        float s = 0.f;
        for (int w = 0; w < BLOCK / 64; w++) s += lds_red[w];
        atomicAdd(ws_loss, s);
    }
    atomicAdd(&ws_hist[tid], lds_hist[tid]);
    atomicAdd(&ws_hist[tid + BLOCK], lds_hist[tid + BLOCK]);

    // scatter the 1.0s (zeros for this block's region guaranteed landed)
    out[OFF_ENC + (size_t)bid * ROWS_PER_BLOCK * K + (size_t)tid * K + (size_t)bkA] = 1.0f;
    out[OFF_ENC + (size_t)bid * ROWS_PER_BLOCK * K + (size_t)(tid + BLOCK) * K + (size_t)bkB] = 1.0f;
}

__global__ __launch_bounds__(K) void vq_finalize(
    const unsigned int* __restrict__ ws_hist,
    const float* __restrict__ ws_loss, float* __restrict__ out)
{
    __shared__ float red[K / 64];
    const int tid = threadIdx.x;
    float p = (float)ws_hist[tid] * (1.0f / (float)N_ROWS);
    float s = p * logf(p + 1e-10f);
    for (int off = 32; off; off >>= 1) s += __shfl_down(s, off, 64);
    if ((tid & 63) == 0) red[tid >> 6] = s;
    __syncthreads();
    if (tid == 0) {
        float t = 0.f;
        for (int w = 0; w < K / 64; w++) t += red[w];
        out[OFF_PERP] = expf(-t);
        float m = ws_loss[0] * (1.0f / (float)(N_ROWS * D));
        out[OFF_LOSS] = m + 0.25f * m;  // q_latent + COMMITMENT_COST * e_latent
    }
}

extern "C" void kernel_launch(void* const* d_in, const int* in_sizes, int n_in,
                              void* d_out, int out_size, void* d_ws, size_t ws_size,
                              hipStream_t stream)
{
    const float* x   = (const float*)d_in[0];   // [16,16384,64] fp32
    const float* emb = (const float*)d_in[1];   // [512,64] fp32
    float* out = (float*)d_out;
    float* ws_loss = (float*)d_ws;                       // 1 float @ 0
    unsigned int* ws_hist = (unsigned int*)d_ws + 16;    // 512 uints @ 64B

    hipMemsetAsync(d_ws, 0, 64 + K * 4, stream);         // ws is 0xAA-poisoned
    vq_main<<<GRID, BLOCK, 0, stream>>>(x, emb, out, ws_loss, ws_hist);
    vq_finalize<<<1, K, 0, stream>>>(ws_hist, ws_loss, out);
}

// Round 2
// 851.601 us; speedup vs baseline: 1.0355x; 1.0355x over previous
//
#include <hip/hip_runtime.h>
#include <math.h>

#define N_ROWS (16 * 16384)          // 262144 rows
#define D 64
#define K 512
#define BLOCK 256
#define RPT 2                        // rows per thread
#define ROWS_PER_BLOCK (BLOCK * RPT) // 512
#define GRID (N_ROWS / ROWS_PER_BLOCK)  // 512 blocks -> 2 per CU
#define CHUNK 128                    // codes per LDS chunk (32 KB)
#define NCHUNK (K / CHUNK)           // 4

// d_out layout (float element offsets), outputs concatenated in return order:
// vq_loss[1], quantized_st[N*D], perplexity[1], encodings[N*K], indices[N]
#define OFF_LOSS 0ULL
#define OFF_Q    1ULL
#define OFF_PERP (1ULL + (unsigned long long)N_ROWS * D)        // 16777217
#define OFF_ENC  (OFF_PERP + 1ULL)                               // 16777218
#define OFF_IDX  (OFF_ENC + (unsigned long long)N_ROWS * K)      // 150994946

// Theory note (R1 post-mortem): vq_main is VALU-issue-bound at ~78 us; the
// uniform-address ds_read_b128 broadcast is near-free (16B return), so the
// LDS chunk path is the right fetch mechanism. The measured dur_us is
// dominated by two ~384 us harness poison fills of the 605 MB output.
__global__ __launch_bounds__(BLOCK)
__attribute__((amdgpu_waves_per_eu(2, 2)))
void vq_main(
    const float* __restrict__ x, const float* __restrict__ emb,
    float* __restrict__ out, float* __restrict__ ws_loss,
    unsigned int* __restrict__ ws_hist)
{
    __shared__ float lds_e[CHUNK * D];        // 32 KB codebook chunk
    __shared__ float lds_se[K];               // 2 KB ||e||^2
    __shared__ unsigned int lds_hist[K];      // 2 KB histogram
    __shared__ float lds_red[BLOCK / 64];

    const int tid = threadIdx.x;
    const int bid = blockIdx.x;
    const int row0 = bid * ROWS_PER_BLOCK + tid;          // thread's row A
    const int row1 = row0 + BLOCK;                        // thread's row B

    lds_hist[tid] = 0;
    lds_hist[tid + BLOCK] = 0;

    // ---- ||e||^2 table once per block (same FMA order as R1/R2 - passed) ----
    for (int k = tid; k < K; k += BLOCK) {
        const float4* e4 = (const float4*)(emb + (size_t)k * D);
        float s = 0.f;
        #pragma unroll
        for (int i = 0; i < 16; i++) {
            float4 e = e4[i];
            s = fmaf(e.x, e.x, s); s = fmaf(e.y, e.y, s);
            s = fmaf(e.z, e.z, s); s = fmaf(e.w, e.w, s);
        }
        lds_se[k] = s;
    }

    // ---- two rows into registers (32 x float4 = 128 VGPR) ----
    float4 xa[16], xb[16];
    {
        const float4* pa = (const float4*)(x + (size_t)row0 * D);
        const float4* pb = (const float4*)(x + (size_t)row1 * D);
        #pragma unroll
        for (int i = 0; i < 16; i++) { xa[i] = pa[i]; xb[i] = pb[i]; }
    }

    // sx per row, same accumulation order as R1/R2
    float sxa, sxb;
    {
        float4 sa = make_float4(0.f, 0.f, 0.f, 0.f);
        float4 sb = make_float4(0.f, 0.f, 0.f, 0.f);
        #pragma unroll
        for (int i = 0; i < 16; i++) {
            sa.x = fmaf(xa[i].x, xa[i].x, sa.x);
            sa.y = fmaf(xa[i].y, xa[i].y, sa.y);
            sa.z = fmaf(xa[i].z, xa[i].z, sa.z);
            sa.w = fmaf(xa[i].w, xa[i].w, sa.w);
            sb.x = fmaf(xb[i].x, xb[i].x, sb.x);
            sb.y = fmaf(xb[i].y, xb[i].y, sb.y);
            sb.z = fmaf(xb[i].z, xb[i].z, sb.z);
            sb.w = fmaf(xb[i].w, xb[i].w, sb.w);
        }
        sxa = (sa.x + sa.y) + (sa.z + sa.w);
        sxb = (sb.x + sb.y) + (sb.z + sb.w);
    }

    // one-hot block region (even float offset -> 8B aligned)
    float2* encb = (float2*)(out + OFF_ENC + (size_t)bid * ROWS_PER_BLOCK * K);
    const float2 z2 = make_float2(0.f, 0.f);

    float bestA = __builtin_inff(), bestB = __builtin_inff();
    int bkA = 0, bkB = 0;

    // ---- argmin over codebook, 4 LDS chunks of 128 codes ----
    for (int c = 0; c < NCHUNK; c++) {
        __syncthreads();  // previous chunk consumed (covers hist/se init on c==0)
        {   // cooperative chunk load: 8 float4/thread, coalesced
            const float4* src = (const float4*)(emb + (size_t)c * CHUNK * D);
            float4* dst = (float4*)lds_e;
            #pragma unroll
            for (int i = 0; i < 8; i++) dst[i * BLOCK + tid] = src[i * BLOCK + tid];
        }
        __syncthreads();

        #pragma unroll 2
        for (int kk = 0; kk < CHUNK; kk++) {
            const int k = c * CHUNK + kk;
            // paced zero-fill: exactly one float2 store per code iteration
            encb[(size_t)k * BLOCK + tid] = z2;

            const float4* ev = (const float4*)(lds_e + kk * D);  // uniform -> broadcast
            float4 a0 = make_float4(0.f, 0.f, 0.f, 0.f);
            float4 a1 = make_float4(0.f, 0.f, 0.f, 0.f);
            #pragma unroll
            for (int i = 0; i < 16; i++) {
                float4 e = ev[i];
                a0.x = fmaf(xa[i].x, e.x, a0.x);
                a0.y = fmaf(xa[i].y, e.y, a0.y);
                a0.z = fmaf(xa[i].z, e.z, a0.z);
                a0.w = fmaf(xa[i].w, e.w, a0.w);
                a1.x = fmaf(xb[i].x, e.x, a1.x);
                a1.y = fmaf(xb[i].y, e.y, a1.y);
                a1.z = fmaf(xb[i].z, e.z, a1.z);
                a1.w = fmaf(xb[i].w, e.w, a1.w);
            }
            float dot0 = (a0.x + a0.y) + (a0.z + a0.w);
            float dot1 = (a1.x + a1.y) + (a1.z + a1.w);
            float se = lds_se[k];
            // reference rounding: t = (sx + se) rounds; d = t - 2*dot (one fma)
            float d0 = fmaf(-2.0f, dot0, sxa + se);
            float d1 = fmaf(-2.0f, dot1, sxb + se);
            if (d0 < bestA) { bestA = d0; bkA = k; }  // strict < = first-min
            if (d1 < bestB) { bestB = d1; bkB = k; }
        }
    }

    // ---- index outputs (as float) ----
    out[OFF_IDX + (size_t)row0] = (float)bkA;
    out[OFF_IDX + (size_t)row1] = (float)bkB;

    // ---- quantized outputs + loss (region base 4B-aligned -> scalar stores) ----
    float loss = 0.f;
    {
        const float4* ea = (const float4*)(emb + (size_t)bkA * D);
        float* q = out + OFF_Q + (size_t)row0 * D;
        #pragma unroll
        for (int i = 0; i < 16; i++) {
            float4 e = ea[i];
            q[i * 4 + 0] = e.x; q[i * 4 + 1] = e.y;
            q[i * 4 + 2] = e.z; q[i * 4 + 3] = e.w;
            float d0 = e.x - xa[i].x, d1 = e.y - xa[i].y;
            float d2 = e.z - xa[i].z, d3 = e.w - xa[i].w;
            loss = fmaf(d0, d0, loss); loss = fmaf(d1, d1, loss);
            loss = fmaf(d2, d2, loss); loss = fmaf(d3, d3, loss);
        }
        const float4* eb = (const float4*)(emb + (size_t)bkB * D);
        q = out + OFF_Q + (size_t)row1 * D;
        #pragma unroll
        for (int i = 0; i < 16; i++) {
            float4 e = eb[i];
            q[i * 4 + 0] = e.x; q[i * 4 + 1] = e.y;
            q[i * 4 + 2] = e.z; q[i * 4 + 3] = e.w;
            float d0 = e.x - xb[i].x, d1 = e.y - xb[i].y;
            float d2 = e.z - xb[i].z, d3 = e.w - xb[i].w;
            loss = fmaf(d0, d0, loss); loss = fmaf(d1, d1, loss);
            loss = fmaf(d2, d2, loss); loss = fmaf(d3, d3, loss);
        }
    }

    // wave reduce then block reduce for loss; LDS histogram
    for (int off = 32; off; off >>= 1) loss += __shfl_down(loss, off, 64);
    const int wave = tid >> 6, lane = tid & 63;
    if (lane == 0) lds_red[wave] = loss;
    atomicAdd(&lds_hist[bkA], 1u);
    atomicAdd(&lds_hist[bkB], 1u);
    __syncthreads();  // drains all zero-fill stores (vmcnt(0) before s_barrier)
    if (tid == 0) {
        float s = 0.f;
        for (int w = 0; w < BLOCK / 64; w++) s += lds_red[w];
        atomicAdd(ws_loss, s);
    }
    atomicAdd(&ws_hist[tid], lds_hist[tid]);
    atomicAdd(&ws_hist[tid + BLOCK], lds_hist[tid + BLOCK]);

    // scatter the 1.0s (zeros for this block's region guaranteed landed)
    out[OFF_ENC + (size_t)bid * ROWS_PER_BLOCK * K + (size_t)tid * K + (size_t)bkA] = 1.0f;
    out[OFF_ENC + (size_t)bid * ROWS_PER_BLOCK * K + (size_t)(tid + BLOCK) * K + (size_t)bkB] = 1.0f;
}

__global__ __launch_bounds__(K) void vq_finalize(
    const unsigned int* __restrict__ ws_hist,
    const float* __restrict__ ws_loss, float* __restrict__ out)
{
    __shared__ float red[K / 64];
    const int tid = threadIdx.x;
    float p = (float)ws_hist[tid] * (1.0f / (float)N_ROWS);
    float s = p * logf(p + 1e-10f);
    for (int off = 32; off; off >>= 1) s += __shfl_down(s, off, 64);
    if ((tid & 63) == 0) red[tid >> 6] = s;
    __syncthreads();
    if (tid == 0) {
        float t = 0.f;
        for (int w = 0; w < K / 64; w++) t += red[w];
        out[OFF_PERP] = expf(-t);
        float m = ws_loss[0] * (1.0f / (float)(N_ROWS * D));
        out[OFF_LOSS] = m + 0.25f * m;  // q_latent + COMMITMENT_COST * e_latent
    }
}

extern "C" void kernel_launch(void* const* d_in, const int* in_sizes, int n_in,
                              void* d_out, int out_size, void* d_ws, size_t ws_size,
                              hipStream_t stream)
{
    const float* x   = (const float*)d_in[0];   // [16,16384,64] fp32
    const float* emb = (const float*)d_in[1];   // [512,64] fp32
    float* out = (float*)d_out;
    float* ws_loss = (float*)d_ws;                       // 1 float @ 0
    unsigned int* ws_hist = (unsigned int*)d_ws + 16;    // 512 uints @ 64B

    hipMemsetAsync(d_ws, 0, 64 + K * 4, stream);         // ws is 0xAA-poisoned
    vq_main<<<GRID, BLOCK, 0, stream>>>(x, emb, out, ws_loss, ws_hist);
    vq_finalize<<<1, K, 0, stream>>>(ws_hist, ws_loss, out);
}